// Round 17
// baseline (1109.614 us; speedup 1.0000x reference)
//
#include <hip/hip_runtime.h>
#include <hip/hip_bf16.h>
#include <math.h>

#define PIX 2304
#define CCH 256
#define CP  589824      // CCH*PIX
#define NCP 1769472     // 3*CP
#define KC  4608        // conv K = 512*9
#define PADR 2512       // padded rows per image

typedef __hip_bfloat16 bf16;
typedef __attribute__((ext_vector_type(8))) short bf16x8;
typedef __attribute__((ext_vector_type(4))) float f32x4;

__device__ __forceinline__ float sigmoidf_(float x){ return 1.f/(1.f+__expf(-x)); }

__device__ __forceinline__ void gl_lds16(const bf16* g, bf16* lds){
    __builtin_amdgcn_global_load_lds(
        (const __attribute__((address_space(1))) void*)g,
        (__attribute__((address_space(3))) void*)lds, 16, 0, 0);
}
#define FENCE() asm volatile("" ::: "memory")

__device__ __forceinline__ float bperm_f(int srcLane, float v){
    return __int_as_float(__builtin_amdgcn_ds_bpermute(srcLane<<2, __float_as_int(v)));
}
__device__ __forceinline__ unsigned packbf(float lo, float hi){
    bf16 a = __float2bfloat16(lo), b = __float2bfloat16(hi);
    return (unsigned)(*(unsigned short*)&a) | ((unsigned)(*(unsigned short*)&b)<<16);
}

// =======================================================================
// Fused flash attention, KVBLK=128 single-buffered (4-sync schedule), now
// with 2 q-subtiles per wave (32 q): each Ks/Vs LDS read feeds 2 MFMAs,
// halving LDS read traffic (the measured bottleneck). 3 waves (192 thr),
// QBLK=96, grid (24,1,9)=216. LDS 64K+64K+24K. Staging: 22 guarded passes
// of stride 192 (pass 21 covers wave 0 only - wave-uniform); vmcnt(21)
// ledger exact for 21-issue waves, over-drains <=1 for wave 0 (safe).
// =======================================================================
__global__ __launch_bounds__(192) void fattn_k(
    const bf16* __restrict__ T, const bf16* __restrict__ Ti,
    const bf16* __restrict__ Khp, const bf16* __restrict__ Vcp,
    bf16* __restrict__ Ob)
{
    __shared__ bf16 Ks[128*256];     // [kv][d], 32 chunks/row, swz ^(row&7)
    __shared__ bf16 Vs[256*128];     // [c][kv], 16 chunks/row, swz ^(row&7)
    __shared__ unsigned Ps[6][1024]; // per (wave,subtile) P 16q x 128kv
    const int z = blockIdx.z, i = z/3, j = z%3;
    const bf16* Q  = ((i==j)? Ti : T) + (long)i*CP;
    const bf16* Kp = Khp + (long)j*CP;
    const bf16* Vp = Vcp + (long)j*CP;
    const int tid = threadIdx.x, l = tid & 63, w = tid >> 6;
    const int g = l>>4, m = l&15;
    const int q0 = blockIdx.x*96 + w*32;

    bf16x8 qf0[8], qf1[8];
    {
        const bf16* qr0 = Q + (long)(q0 + m)*256 + g*8;
        const bf16* qr1 = Q + (long)(q0 + 16 + m)*256 + g*8;
        #pragma unroll
        for (int ks=0; ks<8; ++ks){
            qf0[ks] = *(const bf16x8*)(qr0 + ks*32);
            qf1[ks] = *(const bf16x8*)(qr1 + ks*32);
        }
    }
    f32x4 oacc0[16], oacc1[16];
    #pragma unroll
    for (int nf=0; nf<16; ++nf){
        oacc0[nf] = (f32x4){0.f,0.f,0.f,0.f};
        oacc1[nf] = (f32x4){0.f,0.f,0.f,0.f};
    }
    float mrun0 = -3e38f, lrun0 = 0.f;
    float mrun1 = -3e38f, lrun1 = 0.f;

    // K tile: 128 rows x 256 d = 4096 chunks; 22 guarded passes @192thr
    auto stageK = [&](int t){
        const int kq = t*128;
        #pragma unroll
        for (int u=0; u<22; ++u){
            int idx = u*192 + tid;
            if (idx < 4096){
                int rr = idx>>5, cc = idx&31;
                gl_lds16(Kp + (long)(kq+rr)*256 + ((cc ^ (rr&7))<<3),
                         &Ks[(u*192 + (tid & ~63))*8]);
            }
        }
    };
    // V^T tile: 256 rows x 128 kv = 4096 chunks
    auto stageV = [&](int t){
        const int kq = t*128;
        #pragma unroll
        for (int u=0; u<22; ++u){
            int idx = u*192 + tid;
            if (idx < 4096){
                int rr = idx>>4, cc = idx&15;
                gl_lds16(Vp + (long)rr*2304 + kq + ((cc ^ (rr&7))<<3),
                         &Vs[(u*192 + (tid & ~63))*8]);
            }
        }
    };

    stageK(0); stageV(0);
    char* pw0 = (char*)Ps + (w*2+0)*4096;
    char* pw1 = (char*)Ps + (w*2+1)*4096;
    for (int t=0; t<18; ++t){
        // ---- A: K(t) ready ----
        asm volatile("s_waitcnt vmcnt(21)" ::: "memory");
        __builtin_amdgcn_s_barrier();
        FENCE();

        // ---- QK^T for both subtiles: each kf read feeds 2 MFMAs ----
        f32x4 sacc0[8], sacc1[8];
        #pragma unroll
        for (int nf=0; nf<8; ++nf){
            sacc0[nf] = (f32x4){0.f,0.f,0.f,0.f};
            sacc1[nf] = (f32x4){0.f,0.f,0.f,0.f};
        }
        __builtin_amdgcn_s_setprio(1);
        #pragma unroll
        for (int ks=0; ks<8; ++ks){
            #pragma unroll
            for (int nf=0; nf<8; ++nf){
                int row = nf*16 + m;
                int phys = (ks*4 + g) ^ (row&7);
                bf16x8 kf = *(const bf16x8*)&Ks[row*256 + phys*8];
                sacc0[nf] = __builtin_amdgcn_mfma_f32_16x16x32_bf16(kf, qf0[ks], sacc0[nf], 0,0,0);
                sacc1[nf] = __builtin_amdgcn_mfma_f32_16x16x32_bf16(kf, qf1[ks], sacc1[nf], 0,0,0);
            }
        }
        __builtin_amdgcn_s_setprio(0);
        FENCE();
        __builtin_amdgcn_s_barrier();     // B: K consumed -> restageable
        FENCE();
        if (t+1 < 18) stageK(t+1);

        // ---- softmax subtile 0 (overlaps K staging) ----
        {
            float pmax = -3e38f;
            #pragma unroll
            for (int nf=0; nf<8; ++nf)
                #pragma unroll
                for (int r=0; r<4; ++r) pmax = fmaxf(pmax, sacc0[nf][r]);
            pmax = fmaxf(pmax, __shfl_xor(pmax, 16));
            pmax = fmaxf(pmax, __shfl_xor(pmax, 32));
            if (!__all(pmax - mrun0 <= 8.f)){
                float mn = fmaxf(mrun0, pmax);
                float al = __expf(mrun0 - mn);
                mrun0 = mn;
                lrun0 *= al;
                float ar[4];
                #pragma unroll
                for (int r=0; r<4; ++r) ar[r] = bperm_f((l & 48) | (g*4 + r), al);
                #pragma unroll
                for (int nf=0; nf<16; ++nf)
                    #pragma unroll
                    for (int r=0; r<4; ++r) oacc0[nf][r] *= ar[r];
            }
            float rs = 0.f;
            #pragma unroll
            for (int nf=0; nf<8; ++nf){
                float p0 = __expf(sacc0[nf][0] - mrun0);
                float p1 = __expf(sacc0[nf][1] - mrun0);
                float p2 = __expf(sacc0[nf][2] - mrun0);
                float p3 = __expf(sacc0[nf][3] - mrun0);
                rs += (p0+p1) + (p2+p3);
                unsigned k0 = packbf(p0, p1), k1 = packbf(p2, p3);
                int ba0 = m*256 + ((nf*32 + g*8 + 0) ^ ((m&7)<<4));
                int ba1 = m*256 + ((nf*32 + g*8 + 4) ^ ((m&7)<<4));
                *(unsigned*)(pw0 + ba0) = k0;
                *(unsigned*)(pw0 + ba1) = k1;
            }
            rs += __shfl_xor(rs, 16);
            rs += __shfl_xor(rs, 32);
            lrun0 += rs;
        }
        // ---- softmax subtile 1 ----
        {
            float pmax = -3e38f;
            #pragma unroll
            for (int nf=0; nf<8; ++nf)
                #pragma unroll
                for (int r=0; r<4; ++r) pmax = fmaxf(pmax, sacc1[nf][r]);
            pmax = fmaxf(pmax, __shfl_xor(pmax, 16));
            pmax = fmaxf(pmax, __shfl_xor(pmax, 32));
            if (!__all(pmax - mrun1 <= 8.f)){
                float mn = fmaxf(mrun1, pmax);
                float al = __expf(mrun1 - mn);
                mrun1 = mn;
                lrun1 *= al;
                float ar[4];
                #pragma unroll
                for (int r=0; r<4; ++r) ar[r] = bperm_f((l & 48) | (g*4 + r), al);
                #pragma unroll
                for (int nf=0; nf<16; ++nf)
                    #pragma unroll
                    for (int r=0; r<4; ++r) oacc1[nf][r] *= ar[r];
            }
            float rs = 0.f;
            #pragma unroll
            for (int nf=0; nf<8; ++nf){
                float p0 = __expf(sacc1[nf][0] - mrun1);
                float p1 = __expf(sacc1[nf][1] - mrun1);
                float p2 = __expf(sacc1[nf][2] - mrun1);
                float p3 = __expf(sacc1[nf][3] - mrun1);
                rs += (p0+p1) + (p2+p3);
                unsigned k0 = packbf(p0, p1), k1 = packbf(p2, p3);
                int ba0 = m*256 + ((nf*32 + g*8 + 0) ^ ((m&7)<<4));
                int ba1 = m*256 + ((nf*32 + g*8 + 4) ^ ((m&7)<<4));
                *(unsigned*)(pw1 + ba0) = k0;
                *(unsigned*)(pw1 + ba1) = k1;
            }
            rs += __shfl_xor(rs, 16);
            rs += __shfl_xor(rs, 32);
            lrun1 += rs;
        }
        asm volatile("s_waitcnt lgkmcnt(0)" ::: "memory");
        __builtin_amdgcn_sched_barrier(0);

        // ---- D: V(t) ready ----
        if (t+1 < 18) asm volatile("s_waitcnt vmcnt(21)" ::: "memory");
        else          asm volatile("s_waitcnt vmcnt(0)"  ::: "memory");
        __builtin_amdgcn_s_barrier();
        FENCE();

        // ---- PV: each bv read feeds 2 MFMAs ----
        __builtin_amdgcn_s_setprio(1);
        #pragma unroll
        for (int ks2=0; ks2<4; ++ks2){
            bf16x8 pa0 = *(const bf16x8*)(pw0 + m*256 + ((ks2*64 + g*16) ^ ((m&7)<<4)));
            bf16x8 pa1 = *(const bf16x8*)(pw1 + m*256 + ((ks2*64 + g*16) ^ ((m&7)<<4)));
            #pragma unroll
            for (int nf=0; nf<16; ++nf){
                int row = nf*16 + m;
                int phys = (ks2*4 + g) ^ (row&7);
                bf16x8 bv = *(const bf16x8*)&Vs[row*128 + phys*8];
                oacc0[nf] = __builtin_amdgcn_mfma_f32_16x16x32_bf16(pa0, bv, oacc0[nf], 0,0,0);
                oacc1[nf] = __builtin_amdgcn_mfma_f32_16x16x32_bf16(pa1, bv, oacc1[nf], 0,0,0);
            }
        }
        __builtin_amdgcn_s_setprio(0);
        FENCE();
        __builtin_amdgcn_s_barrier();     // C: V consumed -> restageable
        FENCE();
        if (t+1 < 18) stageV(t+1);
    }

    bf16* ob = Ob + (long)z*CP;
    {
        float linv = 1.f / lrun0;
        float li[4];
        #pragma unroll
        for (int r=0; r<4; ++r) li[r] = bperm_f((l & 48) | (g*4 + r), linv);
        const int prow0 = q0 + g*4;
        #pragma unroll
        for (int nf=0; nf<16; ++nf){
            int c = nf*16 + m;
            #pragma unroll
            for (int r=0; r<4; ++r)
                ob[(long)(prow0+r)*256 + c] = __float2bfloat16(oacc0[nf][r]*li[r]);
        }
    }
    {
        float linv = 1.f / lrun1;
        float li[4];
        #pragma unroll
        for (int r=0; r<4; ++r) li[r] = bperm_f((l & 48) | (g*4 + r), linv);
        const int prow0 = q0 + 16 + g*4;
        #pragma unroll
        for (int nf=0; nf<16; ++nf){
            int c = nf*16 + m;
            #pragma unroll
            for (int r=0; r<4; ++r)
                ob[(long)(prow0+r)*256 + c] = __float2bfloat16(oacc1[nf][r]*li[r]);
        }
    }
}

// =======================================================================
// bf16 MFMA GEMM (t/ti projection), unchanged.
// =======================================================================
template<int BN>
__global__ __launch_bounds__(256) void mgemm_k(
    const bf16* __restrict__ A0, const bf16* __restrict__ B, bf16* __restrict__ ob,
    int M, int lda, int ldb, int ldc,
    long bsB, long bsC, int nzJ, int Ksub)
{
    __shared__ bf16 As[2][128*64];
    __shared__ bf16 Bs[2][BN*64];
    const int jz = blockIdx.z % nzJ;
    const bf16* Ap = A0 + (long)blockIdx.x*128*lda;
    const bf16* Bp = B + jz*bsB + (long)blockIdx.y*BN*ldb;
    const int tid = threadIdx.x, l = tid & 63;
    const int wvu = tid & ~63;
    const int wr = tid>>7, wc = (tid>>6)&1;
    constexpr int NF = BN/32;
    f32x4 acc[4][NF];
    #pragma unroll
    for (int i=0;i<4;++i)
        #pragma unroll
        for (int j=0;j<NF;++j) acc[i][j] = (f32x4){0.f,0.f,0.f,0.f};

    auto stage = [&](int buf, int kb){
        #pragma unroll
        for (int u=0;u<4;++u){
            int idx = u*256 + tid;
            int row = idx>>3, g = (idx&7) ^ (row&7);
            gl_lds16(Ap + (long)row*lda + kb + g*8, &As[buf][(u*256+wvu)*8]);
        }
        #pragma unroll
        for (int u=0;u<BN/32;++u){
            int idx = u*256 + tid;
            int row = idx>>3, g = (idx&7) ^ (row&7);
            gl_lds16(Bp + (long)row*ldb + kb + g*8, &Bs[buf][(u*256+wvu)*8]);
        }
    };

    const int nk = Ksub >> 6;
    stage(0, 0);
    int cur = 0;
    for (int t=0; t<nk; ++t){
        if (t+1 < nk){
            stage(cur^1, (t+1)*64);
            if constexpr (BN==64) asm volatile("s_waitcnt vmcnt(6)" ::: "memory");
            else                  asm volatile("s_waitcnt vmcnt(8)" ::: "memory");
        } else {
            asm volatile("s_waitcnt vmcnt(0)" ::: "memory");
        }
        __builtin_amdgcn_s_barrier();
        FENCE();
        #pragma unroll
        for (int ks=0; ks<64; ks+=32){
            bf16x8 af[4], bfr[NF];
            #pragma unroll
            for (int i=0;i<4;++i){
                int row = wr*64 + i*16 + (l&15);
                af[i] = *(const bf16x8*)&As[cur][row*64 + ((((ks>>3)+(l>>4)) ^ (row&7))<<3)];
            }
            #pragma unroll
            for (int j=0;j<NF;++j){
                int row = wc*(BN/2) + j*16 + (l&15);
                bfr[j] = *(const bf16x8*)&Bs[cur][row*64 + ((((ks>>3)+(l>>4)) ^ (row&7))<<3)];
            }
            #pragma unroll
            for (int i=0;i<4;++i)
                #pragma unroll
                for (int j=0;j<NF;++j)
                    acc[i][j] = __builtin_amdgcn_mfma_f32_16x16x32_bf16(af[i], bfr[j], acc[i][j], 0,0,0);
        }
        FENCE();
        __builtin_amdgcn_s_barrier();
        FENCE();
        cur ^= 1;
    }

    const int mb = blockIdx.x*128 + wr*64, nb = blockIdx.y*BN + wc*(BN/2);
    #pragma unroll
    for (int i=0;i<4;++i)
        #pragma unroll
        for (int j=0;j<NF;++j){
            int gm0 = mb + i*16 + ((l>>4)<<2);
            int gn  = nb + j*16 + (l&15);
            #pragma unroll
            for (int r=0;r<4;++r)
                ob[jz*bsC + (long)(gm0+r)*ldc + gn] = __float2bfloat16(acc[i][j][r]);
        }
}

// =======================================================================
// Fused gate GEMM + j-sum + pad-transpose epilogue (r14 proven, unchanged).
// =======================================================================
__global__ __launch_bounds__(256) void gatemm_k(
    const bf16* __restrict__ gatew, const bf16* __restrict__ Mb9,
    const float* __restrict__ gb, bf16* __restrict__ inpad)
{
    __shared__ bf16 As[2][128*64];
    __shared__ bf16 Bs[2][64*64];
    __shared__ bf16 Ts[64*136];
    const int tid = threadIdx.x, l = tid & 63, wvu = tid & ~63;
    const int wr = tid>>7, wc = (tid>>6)&1;
    const int i = blockIdx.z;
    const bf16* Ap = gatew + (long)blockIdx.x*128*256;
    const int nb0 = blockIdx.y*64;
    f32x4 msum[4][2];
    #pragma unroll
    for (int a=0;a<4;++a){ msum[a][0]=(f32x4){0,0,0,0}; msum[a][1]=(f32x4){0,0,0,0}; }

    for (int j=0; j<3; ++j){
        const bf16* Bp = Mb9 + (long)(i*3+j)*CP + (long)nb0*256;
        f32x4 acc[4][2];
        #pragma unroll
        for (int a=0;a<4;++a){ acc[a][0]=(f32x4){0,0,0,0}; acc[a][1]=(f32x4){0,0,0,0}; }
        auto stage = [&](int buf, int kb){
            #pragma unroll
            for (int u=0;u<4;++u){
                int idx = u*256 + tid;
                int row = idx>>3, g = (idx&7) ^ (row&7);
                gl_lds16(Ap + (long)row*256 + kb + g*8, &As[buf][(u*256+wvu)*8]);
            }
            #pragma unroll
            for (int u=0;u<2;++u){
                int idx = u*256 + tid;
                int row = idx>>3, g = (idx&7) ^ (row&7);
                gl_lds16(Bp + (long)row*256 + kb + g*8, &Bs[buf][(u*256+wvu)*8]);
            }
        };
        stage(0, 0);
        int cur = 0;
        for (int t=0; t<4; ++t){
            if (t+1 < 4){
                stage(cur^1, (t+1)*64);
                asm volatile("s_waitcnt vmcnt(6)" ::: "memory");
            } else {
                asm volatile("s_waitcnt vmcnt(0)" ::: "memory");
            }
            __builtin_amdgcn_s_barrier();
            FENCE();
            #pragma unroll
            for (int ks=0; ks<64; ks+=32){
                bf16x8 af[4], bfr[2];
                #pragma unroll
                for (int a=0;a<4;++a){
                    int row = wr*64 + a*16 + (l&15);
                    af[a] = *(const bf16x8*)&As[cur][row*64 + ((((ks>>3)+(l>>4)) ^ (row&7))<<3)];
                }
                #pragma unroll
                for (int b=0;b<2;++b){
                    int row = wc*32 + b*16 + (l&15);
                    bfr[b] = *(const bf16x8*)&Bs[cur][row*64 + ((((ks>>3)+(l>>4)) ^ (row&7))<<3)];
                }
                #pragma unroll
                for (int a=0;a<4;++a)
                    #pragma unroll
                    for (int b=0;b<2;++b)
                        acc[a][b] = __builtin_amdgcn_mfma_f32_16x16x32_bf16(af[a], bfr[b], acc[a][b], 0,0,0);
            }
            FENCE();
            __builtin_amdgcn_s_barrier();
            FENCE();
            cur ^= 1;
        }
        const bf16* mbz = Mb9 + (long)(i*3+j)*CP;
        const int mb = blockIdx.x*128 + wr*64;
        #pragma unroll
        for (int a=0;a<4;++a)
            #pragma unroll
            for (int b=0;b<2;++b){
                int gm0 = mb + a*16 + ((l>>4)<<2);
                int gn  = nb0 + wc*32 + b*16 + (l&15);
                #pragma unroll
                for (int r=0;r<4;++r){
                    int gm = gm0 + r;
                    float g = sigmoidf_(acc[a][b][r] + gb[gm]);
                    float mv = __bfloat162float(mbz[(long)gn*256 + gm]);
                    msum[a][b][r] += g*mv;
                }
            }
    }
    __syncthreads();
    const int mbl = wr*64;
    #pragma unroll
    for (int a=0;a<4;++a)
        #pragma unroll
        for (int b=0;b<2;++b){
            int cl0 = mbl + a*16 + ((l>>4)<<2);
            int pl  = wc*32 + b*16 + (l&15);
            #pragma unroll
            for (int r=0;r<4;++r)
                Ts[pl*136 + cl0 + r] = __float2bfloat16(msum[a][b][r]);
        }
    __syncthreads();
    const int pl = tid >> 2, seg = tid & 3;
    int p = nb0 + pl;
    int prow = p + 2*(p/48) + 51;
    bf16* dst = inpad + (long)i*PADR*512 + (long)prow*512 + blockIdx.x*128 + seg*32;
    #pragma unroll
    for (int k2=0; k2<4; ++k2)
        *(uint4*)(dst + k2*8) = *(const uint4*)&Ts[pl*136 + seg*32 + k2*8];
}

// =======================================================================
// Implicit-GEMM 3x3 conv, BN=128, split-K x2 (r10 proven, unchanged).
// =======================================================================
__global__ __launch_bounds__(256) void cgemm2_k(
    const bf16* __restrict__ inpad, const bf16* __restrict__ W,
    float* __restrict__ part, int N)
{
    __shared__ bf16 As[2][128*64];
    __shared__ bf16 Bs[2][128*64];
    const int tid = threadIdx.x, l = tid & 63, wvu = tid & ~63;
    const int wr = tid>>7, wc = (tid>>6)&1;
    const int bx = blockIdx.x, by = blockIdx.y, kc = blockIdx.z;
    const int img = bx/18, m0 = (bx - img*18)*128;
    const bf16* Ab = inpad + (long)img*PADR*512;
    const bf16* Bb = W + (long)by*128*KC;
    f32x4 acc[4][4];
    #pragma unroll
    for (int i=0;i<4;++i)
        #pragma unroll
        for (int j=0;j<4;++j) acc[i][j] = (f32x4){0.f,0.f,0.f,0.f};

    auto stageA = [&](int buf, int k0){
        int tap = k0 >> 9, ci0 = k0 & 511;
        int dy = tap/3, dx = tap - 3*dy;
        int shift = (dy-1)*50 + (dx-1);
        #pragma unroll
        for (int u=0;u<4;++u){
            int idx = u*256 + tid;
            int row = idx>>3;
            int om = m0 + row;
            int prow = om + 2*(om/48) + 51 + shift;
            int g = (idx&7) ^ (row&7);
            gl_lds16(Ab + (long)prow*512 + ci0 + g*8, &As[buf][(u*256+wvu)*8]);
        }
    };
    auto stageB = [&](int buf, int k0){
        #pragma unroll
        for (int u=0;u<4;++u){
            int idx = u*256 + tid;
            int row = idx>>3;
            int g = (idx&7) ^ (row&7);
            gl_lds16(Bb + (long)row*KC + k0 + g*8, &Bs[buf][(u*256+wvu)*8]);
        }
    };

    const int kbeg = kc*2304;
    stageA(0, kbeg); stageB(0, kbeg);
    int cur = 0;
    for (int t=0; t<36; ++t){
        if (t+1 < 36){
            stageA(cur^1, kbeg+(t+1)*64); stageB(cur^1, kbeg+(t+1)*64);
            asm volatile("s_waitcnt vmcnt(8)" ::: "memory");
        } else {
            asm volatile("s_waitcnt vmcnt(0)" ::: "memory");
        }
        __builtin_amdgcn_s_barrier();
        FENCE();
        #pragma unroll
        for (int ks=0; ks<64; ks+=32){
            bf16x8 af[4], bfr[4];
            #pragma unroll
            for (int i=0;i<4;++i){
                int row = wr*64 + i*16 + (l&15);
                af[i] = *(const bf16x8*)&As[cur][row*64 + ((((ks>>3)+(l>>4)) ^ (row&7))<<3)];
            }
            #pragma unroll
            for (int j=0;j<4;++j){
                int row = wc*64 + j*16 + (l&15);
                bfr[j] = *(const bf16x8*)&Bs[cur][row*64 + ((((ks>>3)+(l>>4)) ^ (row&7))<<3)];
            }
            #pragma unroll
            for (int i=0;i<4;++i)
                #pragma unroll
                for (int j=0;j<4;++j)
                    acc[i][j] = __builtin_amdgcn_mfma_f32_16x16x32_bf16(af[i], bfr[j], acc[i][j], 0,0,0);
        }
        FENCE();
        __builtin_amdgcn_s_barrier();
        FENCE();
        cur ^= 1;
    }

    float* pbase = part + (long)kc*N*6912 + (long)img*2304;
    #pragma unroll
    for (int i=0;i<4;++i)
        #pragma unroll
        for (int j=0;j<4;++j){
            int gm0 = m0 + wr*64 + i*16 + ((l>>4)<<2);
            int gn  = by*128 + wc*64 + j*16 + (l&15);
            *(f32x4*)&pbase[(long)gn*6912 + gm0] = acc[i][j];
        }
}

// ---- zr reduce (tiled): zg = sigmoid(z); inpad[256:512] = bf16(sigmoid(r)*h) ----
__global__ __launch_bounds__(256) void credzr_k(const float* __restrict__ part,
        const float* __restrict__ bz, const float* __restrict__ br,
        const float* __restrict__ h, float* __restrict__ zg, bf16* __restrict__ inpad)
{
    __shared__ float tz[64][65];
    const int img = blockIdx.z, p0 = blockIdx.x*64, c0 = blockIdx.y*64;
    const int t = threadIdx.x, tx = t&63, tq = t>>6;
    #pragma unroll
    for (int u=0;u<16;++u){
        int cl = tq + u*4, c = c0 + cl;
        long pz = (long)c*6912 + (long)img*2304 + p0 + tx;
        float vz = part[pz] + part[pz + 512L*6912];
        long pr = (long)(c+256)*6912 + (long)img*2304 + p0 + tx;
        float vr = part[pr] + part[pr + 512L*6912];
        long hidx = (long)img*CP + (long)c*PIX + p0 + tx;
        float hv = h[hidx];
        zg[hidx] = sigmoidf_(vz + bz[c]);
        tz[cl][tx] = sigmoidf_(vr + br[c]) * hv;
    }
    __syncthreads();
    #pragma unroll
    for (int u=0;u<16;++u){
        int pl = tq + u*4, p = p0 + pl;
        int prow = p + 2*(p/48) + 51;
        inpad[(long)img*PADR*512 + (long)prow*512 + 256 + c0 + tx] = __float2bfloat16(tz[tx][pl]);
    }
}

// ---- h reduce (tiled): GRU update + emit hp16/hcp16/inpad-h for next iter ----
__global__ __launch_bounds__(256) void credht_k(const float* __restrict__ part,
        const float* __restrict__ bh, const float* __restrict__ zg,
        float* __restrict__ h, bf16* __restrict__ hcp, bf16* __restrict__ hp,
        bf16* __restrict__ inpad)
{
    __shared__ float th[64][65];
    const int img = blockIdx.z, p0 = blockIdx.x*64, c0 = blockIdx.y*64;
    const int t = threadIdx.x, tx = t&63, tq = t>>6;
    #pragma unroll
    for (int u=0;u<16;++u){
        int cl = tq + u*4, c = c0 + cl;
        long pidx = (long)c*6912 + (long)img*2304 + p0 + tx;
        float vv = part[pidx] + part[pidx + 256L*6912];
        float hc = tanhf(vv + bh[c]);
        long hidx = (long)img*CP + (long)c*PIX + p0 + tx;
        float zv = zg[hidx];
        float hn = (1.f - zv)*h[hidx] + zv*hc;
        h[hidx] = hn;
        hcp[hidx] = __float2bfloat16(hn);
        th[cl][tx] = hn;
    }
    __syncthreads();
    #pragma unroll
    for (int u=0;u<16;++u){
        int pl = tq + u*4, p = p0 + pl;
        float val = th[tx][pl];
        hp[(long)img*CP + (long)p*256 + c0 + tx] = __float2bfloat16(val);
        int prow = p + 2*(p/48) + 51;
        inpad[(long)img*PADR*512 + (long)prow*512 + 256 + c0 + tx] = __float2bfloat16(val);
    }
}

// ---- readout reduce ----
__global__ __launch_bounds__(256) void credro_k(const float* __restrict__ part,
        const float* __restrict__ b0, float* __restrict__ o0)
{
    int id = blockIdx.x*256 + threadIdx.x;
    int c = id / 6912, g = id - c*6912;
    int img = g / 2304, p = g - img*2304;
    float v = part[id] + part[id + 256L*6912];
    o0[(long)img*CP + (long)c*PIX + p] = fmaxf(v + b0[c], 0.f);
}

__global__ __launch_bounds__(256) void padtr_k(const float* __restrict__ src,
        bf16* __restrict__ dst, int cofs)
{
    __shared__ float tile[64][65];
    const int img = blockIdx.z, p0 = blockIdx.x*64, c0 = blockIdx.y*64;
    const int t = threadIdx.x, tx = t&63, tq = t>>6;
    #pragma unroll
    for (int u=0;u<16;++u){
        int r = tq + u*4;
        tile[r][tx] = src[(long)img*CP + (long)(c0+r)*PIX + p0 + tx];
    }
    __syncthreads();
    bf16* d = dst + (long)img*PADR*512 + cofs + c0;
    #pragma unroll
    for (int u=0;u<16;++u){
        int pl = tq + u*4;
        int p = p0 + pl;
        int prow = p + 2*(p/48) + 51;
        d[(long)prow*512 + tx] = __float2bfloat16(tile[tx][pl]);
    }
}

__global__ __launch_bounds__(256) void convw_k(const float* __restrict__ src,
        bf16* __restrict__ dst, int total)
{
    int idx = blockIdx.x*256 + threadIdx.x;
    if (idx >= total) return;
    int co = idx / KC, r = idx - co*KC;
    int tap = r >> 9, ci = r & 511;
    dst[idx] = __float2bfloat16(src[(long)co*KC + ci*9 + tap]);
}

__global__ __launch_bounds__(256) void prep_h_k(const float* __restrict__ h,
        bf16* __restrict__ hcp, bf16* __restrict__ hp)
{
    __shared__ float tile[64][65];
    const int i = blockIdx.z, p0 = blockIdx.x*64, c0 = blockIdx.y*64;
    const int t = threadIdx.x, tx = t&63, tq = t>>6;
    #pragma unroll
    for (int s=0;s<16;++s){
        int r = tq + s*4;
        float v = h[(long)i*CP + (long)(c0+r)*PIX + p0 + tx];
        tile[r][tx] = v;
        hcp[(long)i*CP + (long)(c0+r)*PIX + p0 + tx] = __float2bfloat16(v);
    }
    __syncthreads();
    #pragma unroll
    for (int s=0;s<16;++s){
        int r = tq + s*4;
        hp[(long)i*CP + (long)(p0+r)*256 + c0 + tx] = __float2bfloat16(tile[tx][r]);
    }
}

__global__ __launch_bounds__(256) void convert_w_k(const float* __restrict__ wint,
    const float* __restrict__ wintra, const float* __restrict__ gw, bf16* __restrict__ o)
{
    int t = blockIdx.x*256 + threadIdx.x;
    int d = t >> 8, c = t & 255;
    o[t]          = __float2bfloat16(wint[c*256 + d]);
    o[65536 + t]  = __float2bfloat16(wintra[c*256 + d]);
    o[131072 + t] = __float2bfloat16(gw[t]);
}

__global__ __launch_bounds__(256) void backbone_k(
    const float* __restrict__ frames, const float* __restrict__ W,
    const float* __restrict__ bias, float* __restrict__ v, float* __restrict__ h)
{
    __shared__ float wl[3*64*4];
    const int n = blockIdx.z, o0 = blockIdx.y * 4;
    const int p = blockIdx.x * 256 + threadIdx.x;
    const int y = p / 48, x = p % 48;
    for (int e = threadIdx.x; e < 768; e += 256) {
        int o_sel = e / 192, rem = e % 192, ci = rem / 64, k = rem % 64;
        wl[(ci*64 + k)*4 + o_sel] = W[((long)(o0 + o_sel)*3 + ci)*64 + k];
    }
    __syncthreads();
    float acc[4] = {0.f,0.f,0.f,0.f};
    for (int ci = 0; ci < 3; ++ci) {
        const float* src = frames + (((long)n*3 + ci)*384) * 384;
        #pragma unroll
        for (int k = 0; k < 64; ++k) {
            int ky = k >> 3, kx = k & 7;
            float iv = src[(8*y + ky)*384 + 8*x + kx];
            float4 w = ((const float4*)wl)[ci*64 + k];
            acc[0] += iv*w.x; acc[1] += iv*w.y; acc[2] += iv*w.z; acc[3] += iv*w.w;
        }
    }
    #pragma unroll
    for (int oo = 0; oo < 4; ++oo) {
        float r = fmaxf(acc[oo] + bias[o0 + oo], 0.f);
        long idx = ((long)n*CCH + o0 + oo)*PIX + p;
        v[idx] = r; h[idx] = r;
    }
}

__global__ __launch_bounds__(256) void maskpart_k(const float* __restrict__ yin,
        const float* __restrict__ W, float* __restrict__ part)
{
    __shared__ float wl[288];
    const int cb = blockIdx.y * 32;
    for (int e = threadIdx.x; e < 288; e += 256) wl[e] = W[cb*9 + e];
    __syncthreads();
    int id = blockIdx.x*256 + threadIdx.x;
    int n = id / PIX, p = id - n*PIX;
    int y = p / 48, x = p % 48;
    float acc = 0.f;
    for (int ci = 0; ci < 32; ++ci) {
        const float* src = yin + ((long)n*CCH + cb + ci)*PIX;
        #pragma unroll
        for (int dy = 0; dy < 3; ++dy) {
            int yy = y + dy - 1;
            #pragma unroll
            for (int dx = 0; dx < 3; ++dx) {
                int xx = x + dx - 1;
                float iv = (yy >= 0 && yy < 48 && xx >= 0 && xx < 48) ? src[yy*48 + xx] : 0.f;
                acc += iv * wl[ci*9 + dy*3 + dx];
            }
        }
    }
    part[(long)blockIdx.y*(3*PIX) + id] = acc;
}

__global__ __launch_bounds__(256) void maskred_k(const float* __restrict__ part,
        const float* __restrict__ bias, float* __restrict__ out)
{
    int id = blockIdx.x*256 + threadIdx.x;
    float acc = bias[0];
    #pragma unroll
    for (int s = 0; s < 8; ++s) acc += part[(long)s*(3*PIX) + id];
    out[id] = acc;
}

extern "C" void kernel_launch(void* const* d_in, const int* in_sizes, int n_in,
                              void* d_out, int out_size, void* d_ws, size_t ws_size,
                              hipStream_t stream)
{
    const float* frames     = (const float*)d_in[0];
    const float* backbone_w = (const float*)d_in[1];
    const float* backbone_b = (const float*)d_in[2];
    const float* W_intra    = (const float*)d_in[3];
    const float* W_inter    = (const float*)d_in[4];
    const float* gate_w     = (const float*)d_in[5];
    const float* gate_b     = (const float*)d_in[6];
    const float* Wz         = (const float*)d_in[7];
    const float* bz         = (const float*)d_in[8];
    const float* Wr         = (const float*)d_in[9];
    const float* br         = (const float*)d_in[10];
    const float* Wh         = (const float*)d_in[11];
    const float* bh         = (const float*)d_in[12];
    const float* ro_w1      = (const float*)d_in[13];
    const float* ro_b1      = (const float*)d_in[14];
    const float* ro_w2      = (const float*)d_in[15];
    const float* ro_b2      = (const float*)d_in[16];
    float* out = (float*)d_out;
    float* ws  = (float*)d_ws;

    float* h    = ws + 0L*NCP;
    float* v    = ws + 1L*NCP;
    float* zg   = ws + 3L*NCP;
    float* S    = ws + 7L*NCP;

    float* Mb9f   = S;                        // attn: Mb9 bf16 | conv: cpart fp32
    float* hp16f  = S + 7962624;
    float* hcp16f = hp16f + 884736;
    float* t16f   = hcp16f + 884736;
    float* ti16f  = t16f + 884736;
    float* wbase  = S + 11501568;
    bf16* Wint_t   = (bf16*)wbase;
    bf16* Wintra_t = Wint_t + 65536;
    bf16* gatew16  = Wint_t + 131072;
    bf16* cw16     = (bf16*)(wbase + 98304);  // 1024 x 4608 bf16
    bf16* inpad    = (bf16*)(wbase + 98304 + 2359296);
    float* maskp   = wbase + 98304 + 2359296 + 1929216;

    bf16* Mb9    = (bf16*)Mb9f;
    bf16* hp16   = (bf16*)hp16f;
    bf16* hcp16  = (bf16*)hcp16f;
    bf16* t16    = (bf16*)t16f;
    bf16* ti16   = (bf16*)ti16f;
    float* cpart = Mb9f;

    dim3 b256(256);

    hipMemsetAsync(inpad, 0, 3858432*sizeof(bf16), stream);
    backbone_k<<<dim3(9,64,3), b256, 0, stream>>>(frames, backbone_w, backbone_b, v, h);
    convert_w_k<<<dim3(256), b256, 0, stream>>>(W_inter, W_intra, gate_w, Wint_t);
    convw_k<<<dim3(4608), b256, 0, stream>>>(Wz, cw16, 256*KC);
    convw_k<<<dim3(4608), b256, 0, stream>>>(Wr, cw16 + 256L*KC, 256*KC);
    convw_k<<<dim3(4608), b256, 0, stream>>>(Wh, cw16 + 512L*KC, 256*KC);
    convw_k<<<dim3(4608), b256, 0, stream>>>(ro_w1, cw16 + 768L*KC, 256*KC);

    // initial bf16 prep of h (from backbone) + h half of inpad
    prep_h_k<<<dim3(36,4,3), b256, 0, stream>>>(h, hcp16, hp16);
    padtr_k<<<dim3(36,4,3), b256, 0, stream>>>(h, inpad, 256);

    for (int it = 0; it < 3; ++it) {
        // ---- attention phase ----
        mgemm_k<64><<<dim3(54,4,2), b256, 0, stream>>>(hp16, Wint_t, t16,
            6912, 256,256,256, 65536L, 1769472L, 2, 256);
        fattn_k<<<dim3(24,1,9), dim3(192), 0, stream>>>(t16, ti16, hp16, hcp16, Mb9);
        gatemm_k<<<dim3(2,36,3), b256, 0, stream>>>(gatew16, Mb9, gate_b, inpad);
        // ---- conv phase ----
        cgemm2_k<<<dim3(54,4,2), b256, 0, stream>>>(inpad, cw16, cpart, 512);
        credzr_k<<<dim3(36,4,3), b256, 0, stream>>>(cpart, bz, br, h, zg, inpad);
        cgemm2_k<<<dim3(54,2,2), b256, 0, stream>>>(inpad, cw16 + 512L*KC, cpart, 256);
        credht_k<<<dim3(36,4,3), b256, 0, stream>>>(cpart, bh, zg, h, hcp16, hp16, inpad);
    }

    // ---- readout ----
    padtr_k<<<dim3(36,4,3), b256, 0, stream>>>(h, inpad, 0);
    padtr_k<<<dim3(36,4,3), b256, 0, stream>>>(v, inpad, 256);
    cgemm2_k<<<dim3(54,2,2), b256, 0, stream>>>(inpad, cw16 + 768L*KC, cpart, 256);
    credro_k<<<dim3(6912), b256, 0, stream>>>(cpart, ro_b1, zg);
    maskpart_k<<<dim3(27,8), b256, 0, stream>>>(zg, ro_w2, maskp);
    maskred_k<<<dim3(27), b256, 0, stream>>>(maskp, ro_b2, out);
}

// Round 18
// 840.527 us; speedup vs baseline: 1.3201x; 1.3201x over previous
//
#include <hip/hip_runtime.h>
#include <hip/hip_bf16.h>
#include <math.h>

#define PIX 2304
#define CCH 256
#define CP  589824      // CCH*PIX
#define NCP 1769472     // 3*CP
#define KC  4608        // conv K = 512*9
#define PADR 2512       // padded rows per image

typedef __hip_bfloat16 bf16;
typedef __attribute__((ext_vector_type(8))) short bf16x8;
typedef __attribute__((ext_vector_type(4))) float f32x4;

__device__ __forceinline__ float sigmoidf_(float x){ return 1.f/(1.f+__expf(-x)); }

__device__ __forceinline__ void gl_lds16(const bf16* g, bf16* lds){
    __builtin_amdgcn_global_load_lds(
        (const __attribute__((address_space(1))) void*)g,
        (__attribute__((address_space(3))) void*)lds, 16, 0, 0);
}
#define FENCE() asm volatile("" ::: "memory")

__device__ __forceinline__ float bperm_f(int srcLane, float v){
    return __int_as_float(__builtin_amdgcn_ds_bpermute(srcLane<<2, __float_as_int(v)));
}
__device__ __forceinline__ unsigned packbf(float lo, float hi){
    bf16 a = __float2bfloat16(lo), b = __float2bfloat16(hi);
    return (unsigned)(*(unsigned short*)&a) | ((unsigned)(*(unsigned short*)&b)<<16);
}

// =======================================================================
// Fused flash attention (r16-proven, reverted from spilled r17 variant).
// KVBLK=128 single-buffered K & V, 4-sync schedule; QBLK=96 (6 waves).
// Grid (24,1,9)=216. LDS 64K+64K+24K = 152KB.
// =======================================================================
__global__ __launch_bounds__(384) void fattn_k(
    const bf16* __restrict__ T, const bf16* __restrict__ Ti,
    const bf16* __restrict__ Khp, const bf16* __restrict__ Vcp,
    bf16* __restrict__ Ob)
{
    __shared__ bf16 Ks[128*256];     // [kv][d], 32 chunks/row, swz ^(row&7)
    __shared__ bf16 Vs[256*128];     // [c][kv], 16 chunks/row, swz ^(row&7)
    __shared__ unsigned Ps[6][1024]; // per-wave P 16q x 128kv bf16, XOR-chunk
    const int z = blockIdx.z, i = z/3, j = z%3;
    const bf16* Q  = ((i==j)? Ti : T) + (long)i*CP;
    const bf16* Kp = Khp + (long)j*CP;
    const bf16* Vp = Vcp + (long)j*CP;
    const int tid = threadIdx.x, l = tid & 63, w = tid >> 6;
    const int g = l>>4, m = l&15;
    const int q0 = blockIdx.x*96;

    bf16x8 qf[8];
    {
        const bf16* qr = Q + (long)(q0 + w*16 + m)*256 + g*8;
        #pragma unroll
        for (int ks=0; ks<8; ++ks) qf[ks] = *(const bf16x8*)(qr + ks*32);
    }
    f32x4 oacc[16];
    #pragma unroll
    for (int nf=0; nf<16; ++nf) oacc[nf] = (f32x4){0.f,0.f,0.f,0.f};
    float mrun = -3e38f;
    float lrun = 0.f;

    auto stageK = [&](int t){
        const int kq = t*128;
        #pragma unroll
        for (int u=0; u<11; ++u){
            int idx = u*384 + tid;
            if (idx < 4096){
                int rr = idx>>5, cc = idx&31;
                gl_lds16(Kp + (long)(kq+rr)*256 + ((cc ^ (rr&7))<<3),
                         &Ks[(u*384 + (tid & ~63))*8]);
            }
        }
    };
    auto stageV = [&](int t){
        const int kq = t*128;
        #pragma unroll
        for (int u=0; u<11; ++u){
            int idx = u*384 + tid;
            if (idx < 4096){
                int rr = idx>>4, cc = idx&15;
                gl_lds16(Vp + (long)rr*2304 + kq + ((cc ^ (rr&7))<<3),
                         &Vs[(u*384 + (tid & ~63))*8]);
            }
        }
    };

    stageK(0); stageV(0);
    char* pw = (char*)&Ps[w][0];
    for (int t=0; t<18; ++t){
        // ---- A: K(t) ready ----
        asm volatile("s_waitcnt vmcnt(10)" ::: "memory");
        __builtin_amdgcn_s_barrier();
        FENCE();

        // ---- QK^T: sacc[nf] = S^T[kv=nf*16+g*4+r][q=m], kv tile 128 ----
        f32x4 sacc[8];
        #pragma unroll
        for (int nf=0; nf<8; ++nf) sacc[nf] = (f32x4){0.f,0.f,0.f,0.f};
        __builtin_amdgcn_s_setprio(1);
        #pragma unroll
        for (int ks=0; ks<8; ++ks){
            #pragma unroll
            for (int nf=0; nf<8; ++nf){
                int row = nf*16 + m;
                int phys = (ks*4 + g) ^ (row&7);
                bf16x8 kf = *(const bf16x8*)&Ks[row*256 + phys*8];
                sacc[nf] = __builtin_amdgcn_mfma_f32_16x16x32_bf16(kf, qf[ks], sacc[nf], 0,0,0);
            }
        }
        __builtin_amdgcn_s_setprio(0);
        FENCE();
        __builtin_amdgcn_s_barrier();     // B: K consumed -> restageable
        FENCE();
        if (t+1 < 18) stageK(t+1);

        // ---- in-lane softmax for q-column m (overlaps K staging) ----
        float pmax = -3e38f;
        #pragma unroll
        for (int nf=0; nf<8; ++nf)
            #pragma unroll
            for (int r=0; r<4; ++r) pmax = fmaxf(pmax, sacc[nf][r]);
        pmax = fmaxf(pmax, __shfl_xor(pmax, 16));
        pmax = fmaxf(pmax, __shfl_xor(pmax, 32));
        if (!__all(pmax - mrun <= 8.f)){
            float mn = fmaxf(mrun, pmax);
            float al = __expf(mrun - mn);
            mrun = mn;
            lrun *= al;
            float ar[4];
            #pragma unroll
            for (int r=0; r<4; ++r) ar[r] = bperm_f((l & 48) | (g*4 + r), al);
            #pragma unroll
            for (int nf=0; nf<16; ++nf)
                #pragma unroll
                for (int r=0; r<4; ++r) oacc[nf][r] *= ar[r];
        }
        float rs = 0.f;
        unsigned pk[8][2];
        #pragma unroll
        for (int nf=0; nf<8; ++nf){
            float p0 = __expf(sacc[nf][0] - mrun);
            float p1 = __expf(sacc[nf][1] - mrun);
            float p2 = __expf(sacc[nf][2] - mrun);
            float p3 = __expf(sacc[nf][3] - mrun);
            rs += (p0+p1) + (p2+p3);
            pk[nf][0] = packbf(p0, p1);
            pk[nf][1] = packbf(p2, p3);
        }
        rs += __shfl_xor(rs, 16);
        rs += __shfl_xor(rs, 32);
        lrun += rs;
        // P -> LDS packed u32 (per-wave region, XOR-chunk layout, row=256B)
        #pragma unroll
        for (int nf=0; nf<8; ++nf)
            #pragma unroll
            for (int s=0; s<2; ++s){
                int ba = m*256 + ((nf*32 + g*8 + s*4) ^ ((m&7)<<4));
                *(unsigned*)(pw + ba) = pk[nf][s];
            }
        asm volatile("s_waitcnt lgkmcnt(0)" ::: "memory");
        __builtin_amdgcn_sched_barrier(0);

        // ---- D: V(t) ready ----
        if (t+1 < 18) asm volatile("s_waitcnt vmcnt(10)" ::: "memory");
        else          asm volatile("s_waitcnt vmcnt(0)"  ::: "memory");
        __builtin_amdgcn_s_barrier();
        FENCE();

        // ---- PV: O[q][c] += P * V (4 k-steps of 32) ----
        __builtin_amdgcn_s_setprio(1);
        #pragma unroll
        for (int ks2=0; ks2<4; ++ks2){
            bf16x8 pa = *(const bf16x8*)(pw + m*256 + ((ks2*64 + g*16) ^ ((m&7)<<4)));
            #pragma unroll
            for (int nf=0; nf<16; ++nf){
                int row = nf*16 + m;
                int phys = (ks2*4 + g) ^ (row&7);
                bf16x8 bv = *(const bf16x8*)&Vs[row*128 + phys*8];
                oacc[nf] = __builtin_amdgcn_mfma_f32_16x16x32_bf16(pa, bv, oacc[nf], 0,0,0);
            }
        }
        __builtin_amdgcn_s_setprio(0);
        FENCE();
        __builtin_amdgcn_s_barrier();     // C: V consumed -> restageable
        FENCE();
        if (t+1 < 18) stageV(t+1);
    }

    float linv = 1.f / lrun;
    float li[4];
    #pragma unroll
    for (int r=0; r<4; ++r) li[r] = bperm_f((l & 48) | (g*4 + r), linv);
    bf16* ob = Ob + (long)z*CP;
    const int prow0 = q0 + w*16 + g*4;
    #pragma unroll
    for (int nf=0; nf<16; ++nf){
        int c = nf*16 + m;
        #pragma unroll
        for (int r=0; r<4; ++r)
            ob[(long)(prow0+r)*256 + c] = __float2bfloat16(oacc[nf][r]*li[r]);
    }
}

// =======================================================================
// bf16 MFMA GEMM (t/ti projection), unchanged.
// =======================================================================
template<int BN>
__global__ __launch_bounds__(256) void mgemm_k(
    const bf16* __restrict__ A0, const bf16* __restrict__ B, bf16* __restrict__ ob,
    int M, int lda, int ldb, int ldc,
    long bsB, long bsC, int nzJ, int Ksub)
{
    __shared__ bf16 As[2][128*64];
    __shared__ bf16 Bs[2][BN*64];
    const int jz = blockIdx.z % nzJ;
    const bf16* Ap = A0 + (long)blockIdx.x*128*lda;
    const bf16* Bp = B + jz*bsB + (long)blockIdx.y*BN*ldb;
    const int tid = threadIdx.x, l = tid & 63;
    const int wvu = tid & ~63;
    const int wr = tid>>7, wc = (tid>>6)&1;
    constexpr int NF = BN/32;
    f32x4 acc[4][NF];
    #pragma unroll
    for (int i=0;i<4;++i)
        #pragma unroll
        for (int j=0;j<NF;++j) acc[i][j] = (f32x4){0.f,0.f,0.f,0.f};

    auto stage = [&](int buf, int kb){
        #pragma unroll
        for (int u=0;u<4;++u){
            int idx = u*256 + tid;
            int row = idx>>3, g = (idx&7) ^ (row&7);
            gl_lds16(Ap + (long)row*lda + kb + g*8, &As[buf][(u*256+wvu)*8]);
        }
        #pragma unroll
        for (int u=0;u<BN/32;++u){
            int idx = u*256 + tid;
            int row = idx>>3, g = (idx&7) ^ (row&7);
            gl_lds16(Bp + (long)row*ldb + kb + g*8, &Bs[buf][(u*256+wvu)*8]);
        }
    };

    const int nk = Ksub >> 6;
    stage(0, 0);
    int cur = 0;
    for (int t=0; t<nk; ++t){
        if (t+1 < nk){
            stage(cur^1, (t+1)*64);
            if constexpr (BN==64) asm volatile("s_waitcnt vmcnt(6)" ::: "memory");
            else                  asm volatile("s_waitcnt vmcnt(8)" ::: "memory");
        } else {
            asm volatile("s_waitcnt vmcnt(0)" ::: "memory");
        }
        __builtin_amdgcn_s_barrier();
        FENCE();
        #pragma unroll
        for (int ks=0; ks<64; ks+=32){
            bf16x8 af[4], bfr[NF];
            #pragma unroll
            for (int i=0;i<4;++i){
                int row = wr*64 + i*16 + (l&15);
                af[i] = *(const bf16x8*)&As[cur][row*64 + ((((ks>>3)+(l>>4)) ^ (row&7))<<3)];
            }
            #pragma unroll
            for (int j=0;j<NF;++j){
                int row = wc*(BN/2) + j*16 + (l&15);
                bfr[j] = *(const bf16x8*)&Bs[cur][row*64 + ((((ks>>3)+(l>>4)) ^ (row&7))<<3)];
            }
            #pragma unroll
            for (int i=0;i<4;++i)
                #pragma unroll
                for (int j=0;j<NF;++j)
                    acc[i][j] = __builtin_amdgcn_mfma_f32_16x16x32_bf16(af[i], bfr[j], acc[i][j], 0,0,0);
        }
        FENCE();
        __builtin_amdgcn_s_barrier();
        FENCE();
        cur ^= 1;
    }

    const int mb = blockIdx.x*128 + wr*64, nb = blockIdx.y*BN + wc*(BN/2);
    #pragma unroll
    for (int i=0;i<4;++i)
        #pragma unroll
        for (int j=0;j<NF;++j){
            int gm0 = mb + i*16 + ((l>>4)<<2);
            int gn  = nb + j*16 + (l&15);
            #pragma unroll
            for (int r=0;r<4;++r)
                ob[jz*bsC + (long)(gm0+r)*ldc + gn] = __float2bfloat16(acc[i][j][r]);
        }
}

// =======================================================================
// Fused gate GEMM + j-sum + pad-transpose epilogue (r14 proven, unchanged).
// =======================================================================
__global__ __launch_bounds__(256) void gatemm_k(
    const bf16* __restrict__ gatew, const bf16* __restrict__ Mb9,
    const float* __restrict__ gb, bf16* __restrict__ inpad)
{
    __shared__ bf16 As[2][128*64];
    __shared__ bf16 Bs[2][64*64];
    __shared__ bf16 Ts[64*136];
    const int tid = threadIdx.x, l = tid & 63, wvu = tid & ~63;
    const int wr = tid>>7, wc = (tid>>6)&1;
    const int i = blockIdx.z;
    const bf16* Ap = gatew + (long)blockIdx.x*128*256;
    const int nb0 = blockIdx.y*64;
    f32x4 msum[4][2];
    #pragma unroll
    for (int a=0;a<4;++a){ msum[a][0]=(f32x4){0,0,0,0}; msum[a][1]=(f32x4){0,0,0,0}; }

    for (int j=0; j<3; ++j){
        const bf16* Bp = Mb9 + (long)(i*3+j)*CP + (long)nb0*256;
        f32x4 acc[4][2];
        #pragma unroll
        for (int a=0;a<4;++a){ acc[a][0]=(f32x4){0,0,0,0}; acc[a][1]=(f32x4){0,0,0,0}; }
        auto stage = [&](int buf, int kb){
            #pragma unroll
            for (int u=0;u<4;++u){
                int idx = u*256 + tid;
                int row = idx>>3, g = (idx&7) ^ (row&7);
                gl_lds16(Ap + (long)row*256 + kb + g*8, &As[buf][(u*256+wvu)*8]);
            }
            #pragma unroll
            for (int u=0;u<2;++u){
                int idx = u*256 + tid;
                int row = idx>>3, g = (idx&7) ^ (row&7);
                gl_lds16(Bp + (long)row*256 + kb + g*8, &Bs[buf][(u*256+wvu)*8]);
            }
        };
        stage(0, 0);
        int cur = 0;
        for (int t=0; t<4; ++t){
            if (t+1 < 4){
                stage(cur^1, (t+1)*64);
                asm volatile("s_waitcnt vmcnt(6)" ::: "memory");
            } else {
                asm volatile("s_waitcnt vmcnt(0)" ::: "memory");
            }
            __builtin_amdgcn_s_barrier();
            FENCE();
            #pragma unroll
            for (int ks=0; ks<64; ks+=32){
                bf16x8 af[4], bfr[2];
                #pragma unroll
                for (int a=0;a<4;++a){
                    int row = wr*64 + a*16 + (l&15);
                    af[a] = *(const bf16x8*)&As[cur][row*64 + ((((ks>>3)+(l>>4)) ^ (row&7))<<3)];
                }
                #pragma unroll
                for (int b=0;b<2;++b){
                    int row = wc*32 + b*16 + (l&15);
                    bfr[b] = *(const bf16x8*)&Bs[cur][row*64 + ((((ks>>3)+(l>>4)) ^ (row&7))<<3)];
                }
                #pragma unroll
                for (int a=0;a<4;++a)
                    #pragma unroll
                    for (int b=0;b<2;++b)
                        acc[a][b] = __builtin_amdgcn_mfma_f32_16x16x32_bf16(af[a], bfr[b], acc[a][b], 0,0,0);
            }
            FENCE();
            __builtin_amdgcn_s_barrier();
            FENCE();
            cur ^= 1;
        }
        const bf16* mbz = Mb9 + (long)(i*3+j)*CP;
        const int mb = blockIdx.x*128 + wr*64;
        #pragma unroll
        for (int a=0;a<4;++a)
            #pragma unroll
            for (int b=0;b<2;++b){
                int gm0 = mb + a*16 + ((l>>4)<<2);
                int gn  = nb0 + wc*32 + b*16 + (l&15);
                #pragma unroll
                for (int r=0;r<4;++r){
                    int gm = gm0 + r;
                    float g = sigmoidf_(acc[a][b][r] + gb[gm]);
                    float mv = __bfloat162float(mbz[(long)gn*256 + gm]);
                    msum[a][b][r] += g*mv;
                }
            }
    }
    __syncthreads();
    const int mbl = wr*64;
    #pragma unroll
    for (int a=0;a<4;++a)
        #pragma unroll
        for (int b=0;b<2;++b){
            int cl0 = mbl + a*16 + ((l>>4)<<2);
            int pl  = wc*32 + b*16 + (l&15);
            #pragma unroll
            for (int r=0;r<4;++r)
                Ts[pl*136 + cl0 + r] = __float2bfloat16(msum[a][b][r]);
        }
    __syncthreads();
    const int pl = tid >> 2, seg = tid & 3;
    int p = nb0 + pl;
    int prow = p + 2*(p/48) + 51;
    bf16* dst = inpad + (long)i*PADR*512 + (long)prow*512 + blockIdx.x*128 + seg*32;
    #pragma unroll
    for (int k2=0; k2<4; ++k2)
        *(uint4*)(dst + k2*8) = *(const uint4*)&Ts[pl*136 + seg*32 + k2*8];
}

// =======================================================================
// Implicit-GEMM 3x3 conv, BN=128, split-K x2 (r10 proven, unchanged).
// =======================================================================
__global__ __launch_bounds__(256) void cgemm2_k(
    const bf16* __restrict__ inpad, const bf16* __restrict__ W,
    float* __restrict__ part, int N)
{
    __shared__ bf16 As[2][128*64];
    __shared__ bf16 Bs[2][128*64];
    const int tid = threadIdx.x, l = tid & 63, wvu = tid & ~63;
    const int wr = tid>>7, wc = (tid>>6)&1;
    const int bx = blockIdx.x, by = blockIdx.y, kc = blockIdx.z;
    const int img = bx/18, m0 = (bx - img*18)*128;
    const bf16* Ab = inpad + (long)img*PADR*512;
    const bf16* Bb = W + (long)by*128*KC;
    f32x4 acc[4][4];
    #pragma unroll
    for (int i=0;i<4;++i)
        #pragma unroll
        for (int j=0;j<4;++j) acc[i][j] = (f32x4){0.f,0.f,0.f,0.f};

    auto stageA = [&](int buf, int k0){
        int tap = k0 >> 9, ci0 = k0 & 511;
        int dy = tap/3, dx = tap - 3*dy;
        int shift = (dy-1)*50 + (dx-1);
        #pragma unroll
        for (int u=0;u<4;++u){
            int idx = u*256 + tid;
            int row = idx>>3;
            int om = m0 + row;
            int prow = om + 2*(om/48) + 51 + shift;
            int g = (idx&7) ^ (row&7);
            gl_lds16(Ab + (long)prow*512 + ci0 + g*8, &As[buf][(u*256+wvu)*8]);
        }
    };
    auto stageB = [&](int buf, int k0){
        #pragma unroll
        for (int u=0;u<4;++u){
            int idx = u*256 + tid;
            int row = idx>>3;
            int g = (idx&7) ^ (row&7);
            gl_lds16(Bb + (long)row*KC + k0 + g*8, &Bs[buf][(u*256+wvu)*8]);
        }
    };

    const int kbeg = kc*2304;
    stageA(0, kbeg); stageB(0, kbeg);
    int cur = 0;
    for (int t=0; t<36; ++t){
        if (t+1 < 36){
            stageA(cur^1, kbeg+(t+1)*64); stageB(cur^1, kbeg+(t+1)*64);
            asm volatile("s_waitcnt vmcnt(8)" ::: "memory");
        } else {
            asm volatile("s_waitcnt vmcnt(0)" ::: "memory");
        }
        __builtin_amdgcn_s_barrier();
        FENCE();
        #pragma unroll
        for (int ks=0; ks<64; ks+=32){
            bf16x8 af[4], bfr[4];
            #pragma unroll
            for (int i=0;i<4;++i){
                int row = wr*64 + i*16 + (l&15);
                af[i] = *(const bf16x8*)&As[cur][row*64 + ((((ks>>3)+(l>>4)) ^ (row&7))<<3)];
            }
            #pragma unroll
            for (int j=0;j<4;++j){
                int row = wc*64 + j*16 + (l&15);
                bfr[j] = *(const bf16x8*)&Bs[cur][row*64 + ((((ks>>3)+(l>>4)) ^ (row&7))<<3)];
            }
            #pragma unroll
            for (int i=0;i<4;++i)
                #pragma unroll
                for (int j=0;j<4;++j)
                    acc[i][j] = __builtin_amdgcn_mfma_f32_16x16x32_bf16(af[i], bfr[j], acc[i][j], 0,0,0);
        }
        FENCE();
        __builtin_amdgcn_s_barrier();
        FENCE();
        cur ^= 1;
    }

    float* pbase = part + (long)kc*N*6912 + (long)img*2304;
    #pragma unroll
    for (int i=0;i<4;++i)
        #pragma unroll
        for (int j=0;j<4;++j){
            int gm0 = m0 + wr*64 + i*16 + ((l>>4)<<2);
            int gn  = by*128 + wc*64 + j*16 + (l&15);
            *(f32x4*)&pbase[(long)gn*6912 + gm0] = acc[i][j];
        }
}

// ---- zr reduce (tiled): zg = sigmoid(z); inpad[256:512] = bf16(sigmoid(r)*h) ----
__global__ __launch_bounds__(256) void credzr_k(const float* __restrict__ part,
        const float* __restrict__ bz, const float* __restrict__ br,
        const float* __restrict__ h, float* __restrict__ zg, bf16* __restrict__ inpad)
{
    __shared__ float tz[64][65];
    const int img = blockIdx.z, p0 = blockIdx.x*64, c0 = blockIdx.y*64;
    const int t = threadIdx.x, tx = t&63, tq = t>>6;
    #pragma unroll
    for (int u=0;u<16;++u){
        int cl = tq + u*4, c = c0 + cl;
        long pz = (long)c*6912 + (long)img*2304 + p0 + tx;
        float vz = part[pz] + part[pz + 512L*6912];
        long pr = (long)(c+256)*6912 + (long)img*2304 + p0 + tx;
        float vr = part[pr] + part[pr + 512L*6912];
        long hidx = (long)img*CP + (long)c*PIX + p0 + tx;
        float hv = h[hidx];
        zg[hidx] = sigmoidf_(vz + bz[c]);
        tz[cl][tx] = sigmoidf_(vr + br[c]) * hv;
    }
    __syncthreads();
    #pragma unroll
    for (int u=0;u<16;++u){
        int pl = tq + u*4, p = p0 + pl;
        int prow = p + 2*(p/48) + 51;
        inpad[(long)img*PADR*512 + (long)prow*512 + 256 + c0 + tx] = __float2bfloat16(tz[tx][pl]);
    }
}

// ---- h reduce (tiled): GRU update + emit hp16/hcp16/inpad-h for next iter ----
__global__ __launch_bounds__(256) void credht_k(const float* __restrict__ part,
        const float* __restrict__ bh, const float* __restrict__ zg,
        float* __restrict__ h, bf16* __restrict__ hcp, bf16* __restrict__ hp,
        bf16* __restrict__ inpad)
{
    __shared__ float th[64][65];
    const int img = blockIdx.z, p0 = blockIdx.x*64, c0 = blockIdx.y*64;
    const int t = threadIdx.x, tx = t&63, tq = t>>6;
    #pragma unroll
    for (int u=0;u<16;++u){
        int cl = tq + u*4, c = c0 + cl;
        long pidx = (long)c*6912 + (long)img*2304 + p0 + tx;
        float vv = part[pidx] + part[pidx + 256L*6912];
        float hc = tanhf(vv + bh[c]);
        long hidx = (long)img*CP + (long)c*PIX + p0 + tx;
        float zv = zg[hidx];
        float hn = (1.f - zv)*h[hidx] + zv*hc;
        h[hidx] = hn;
        hcp[hidx] = __float2bfloat16(hn);
        th[cl][tx] = hn;
    }
    __syncthreads();
    #pragma unroll
    for (int u=0;u<16;++u){
        int pl = tq + u*4, p = p0 + pl;
        float val = th[tx][pl];
        hp[(long)img*CP + (long)p*256 + c0 + tx] = __float2bfloat16(val);
        int prow = p + 2*(p/48) + 51;
        inpad[(long)img*PADR*512 + (long)prow*512 + 256 + c0 + tx] = __float2bfloat16(val);
    }
}

// ---- readout reduce ----
__global__ __launch_bounds__(256) void credro_k(const float* __restrict__ part,
        const float* __restrict__ b0, float* __restrict__ o0)
{
    int id = blockIdx.x*256 + threadIdx.x;
    int c = id / 6912, g = id - c*6912;
    int img = g / 2304, p = g - img*2304;
    float v = part[id] + part[id + 256L*6912];
    o0[(long)img*CP + (long)c*PIX + p] = fmaxf(v + b0[c], 0.f);
}

__global__ __launch_bounds__(256) void padtr_k(const float* __restrict__ src,
        bf16* __restrict__ dst, int cofs)
{
    __shared__ float tile[64][65];
    const int img = blockIdx.z, p0 = blockIdx.x*64, c0 = blockIdx.y*64;
    const int t = threadIdx.x, tx = t&63, tq = t>>6;
    #pragma unroll
    for (int u=0;u<16;++u){
        int r = tq + u*4;
        tile[r][tx] = src[(long)img*CP + (long)(c0+r)*PIX + p0 + tx];
    }
    __syncthreads();
    bf16* d = dst + (long)img*PADR*512 + cofs + c0;
    #pragma unroll
    for (int u=0;u<16;++u){
        int pl = tq + u*4;
        int p = p0 + pl;
        int prow = p + 2*(p/48) + 51;
        d[(long)prow*512 + tx] = __float2bfloat16(tile[tx][pl]);
    }
}

// ---- conv weight repack; SWAP swaps 256-channel halves (for readout) ----
template<int SWAP>
__global__ __launch_bounds__(256) void convw_k(const float* __restrict__ src,
        bf16* __restrict__ dst, int total)
{
    int idx = blockIdx.x*256 + threadIdx.x;
    if (idx >= total) return;
    int co = idx / KC, r = idx - co*KC;
    int tap = r >> 9, ci = r & 511;
    int ci_src = SWAP ? ((ci + 256) & 511) : ci;
    dst[idx] = __float2bfloat16(src[(long)co*KC + ci_src*9 + tap]);
}

__global__ __launch_bounds__(256) void prep_h_k(const float* __restrict__ h,
        bf16* __restrict__ hcp, bf16* __restrict__ hp)
{
    __shared__ float tile[64][65];
    const int i = blockIdx.z, p0 = blockIdx.x*64, c0 = blockIdx.y*64;
    const int t = threadIdx.x, tx = t&63, tq = t>>6;
    #pragma unroll
    for (int s=0;s<16;++s){
        int r = tq + s*4;
        float v = h[(long)i*CP + (long)(c0+r)*PIX + p0 + tx];
        tile[r][tx] = v;
        hcp[(long)i*CP + (long)(c0+r)*PIX + p0 + tx] = __float2bfloat16(v);
    }
    __syncthreads();
    #pragma unroll
    for (int s=0;s<16;++s){
        int r = tq + s*4;
        hp[(long)i*CP + (long)(p0+r)*256 + c0 + tx] = __float2bfloat16(tile[tx][r]);
    }
}

__global__ __launch_bounds__(256) void convert_w_k(const float* __restrict__ wint,
    const float* __restrict__ wintra, const float* __restrict__ gw, bf16* __restrict__ o)
{
    int t = blockIdx.x*256 + threadIdx.x;
    int d = t >> 8, c = t & 255;
    o[t]          = __float2bfloat16(wint[c*256 + d]);
    o[65536 + t]  = __float2bfloat16(wintra[c*256 + d]);
    o[131072 + t] = __float2bfloat16(gw[t]);
}

__global__ __launch_bounds__(256) void backbone_k(
    const float* __restrict__ frames, const float* __restrict__ W,
    const float* __restrict__ bias, float* __restrict__ v, float* __restrict__ h)
{
    __shared__ float wl[3*64*4];
    const int n = blockIdx.z, o0 = blockIdx.y * 4;
    const int p = blockIdx.x * 256 + threadIdx.x;
    const int y = p / 48, x = p % 48;
    for (int e = threadIdx.x; e < 768; e += 256) {
        int o_sel = e / 192, rem = e % 192, ci = rem / 64, k = rem % 64;
        wl[(ci*64 + k)*4 + o_sel] = W[((long)(o0 + o_sel)*3 + ci)*64 + k];
    }
    __syncthreads();
    float acc[4] = {0.f,0.f,0.f,0.f};
    for (int ci = 0; ci < 3; ++ci) {
        const float* src = frames + (((long)n*3 + ci)*384) * 384;
        #pragma unroll
        for (int k = 0; k < 64; ++k) {
            int ky = k >> 3, kx = k & 7;
            float iv = src[(8*y + ky)*384 + 8*x + kx];
            float4 w = ((const float4*)wl)[ci*64 + k];
            acc[0] += iv*w.x; acc[1] += iv*w.y; acc[2] += iv*w.z; acc[3] += iv*w.w;
        }
    }
    #pragma unroll
    for (int oo = 0; oo < 4; ++oo) {
        float r = fmaxf(acc[oo] + bias[o0 + oo], 0.f);
        long idx = ((long)n*CCH + o0 + oo)*PIX + p;
        v[idx] = r; h[idx] = r;
    }
}

__global__ __launch_bounds__(256) void maskpart_k(const float* __restrict__ yin,
        const float* __restrict__ W, float* __restrict__ part)
{
    __shared__ float wl[288];
    const int cb = blockIdx.y * 32;
    for (int e = threadIdx.x; e < 288; e += 256) wl[e] = W[cb*9 + e];
    __syncthreads();
    int id = blockIdx.x*256 + threadIdx.x;
    int n = id / PIX, p = id - n*PIX;
    int y = p / 48, x = p % 48;
    float acc = 0.f;
    for (int ci = 0; ci < 32; ++ci) {
        const float* src = yin + ((long)n*CCH + cb + ci)*PIX;
        #pragma unroll
        for (int dy = 0; dy < 3; ++dy) {
            int yy = y + dy - 1;
            #pragma unroll
            for (int dx = 0; dx < 3; ++dx) {
                int xx = x + dx - 1;
                float iv = (yy >= 0 && yy < 48 && xx >= 0 && xx < 48) ? src[yy*48 + xx] : 0.f;
                acc += iv * wl[ci*9 + dy*3 + dx];
            }
        }
    }
    part[(long)blockIdx.y*(3*PIX) + id] = acc;
}

__global__ __launch_bounds__(256) void maskred_k(const float* __restrict__ part,
        const float* __restrict__ bias, float* __restrict__ out)
{
    int id = blockIdx.x*256 + threadIdx.x;
    float acc = bias[0];
    #pragma unroll
    for (int s = 0; s < 8; ++s) acc += part[(long)s*(3*PIX) + id];
    out[id] = acc;
}

extern "C" void kernel_launch(void* const* d_in, const int* in_sizes, int n_in,
                              void* d_out, int out_size, void* d_ws, size_t ws_size,
                              hipStream_t stream)
{
    const float* frames     = (const float*)d_in[0];
    const float* backbone_w = (const float*)d_in[1];
    const float* backbone_b = (const float*)d_in[2];
    const float* W_intra    = (const float*)d_in[3];
    const float* W_inter    = (const float*)d_in[4];
    const float* gate_w     = (const float*)d_in[5];
    const float* gate_b     = (const float*)d_in[6];
    const float* Wz         = (const float*)d_in[7];
    const float* bz         = (const float*)d_in[8];
    const float* Wr         = (const float*)d_in[9];
    const float* br         = (const float*)d_in[10];
    const float* Wh         = (const float*)d_in[11];
    const float* bh         = (const float*)d_in[12];
    const float* ro_w1      = (const float*)d_in[13];
    const float* ro_b1      = (const float*)d_in[14];
    const float* ro_w2      = (const float*)d_in[15];
    const float* ro_b2      = (const float*)d_in[16];
    float* out = (float*)d_out;
    float* ws  = (float*)d_ws;

    float* h    = ws + 0L*NCP;
    float* v    = ws + 1L*NCP;
    float* zg   = ws + 3L*NCP;
    float* S    = ws + 7L*NCP;

    float* Mb9f   = S;                        // attn: Mb9 bf16 | conv: cpart fp32
    float* hp16f  = S + 7962624;
    float* hcp16f = hp16f + 884736;
    float* t16f   = hcp16f + 884736;
    float* ti16f  = t16f + 884736;
    float* wbase  = S + 11501568;
    bf16* Wint_t   = (bf16*)wbase;
    bf16* Wintra_t = Wint_t + 65536;
    bf16* gatew16  = Wint_t + 131072;
    bf16* cw16     = (bf16*)(wbase + 98304);  // 1024 x 4608 bf16
    bf16* inpad    = (bf16*)(wbase + 98304 + 2359296);
    float* maskp   = wbase + 98304 + 2359296 + 1929216;

    bf16* Mb9    = (bf16*)Mb9f;
    bf16* hp16   = (bf16*)hp16f;
    bf16* hcp16  = (bf16*)hcp16f;
    bf16* t16    = (bf16*)t16f;
    bf16* ti16   = (bf16*)ti16f;
    float* cpart = Mb9f;

    dim3 b256(256);

    hipMemsetAsync(inpad, 0, 3858432*sizeof(bf16), stream);
    backbone_k<<<dim3(9,64,3), b256, 0, stream>>>(frames, backbone_w, backbone_b, v, h);
    convert_w_k<<<dim3(256), b256, 0, stream>>>(W_inter, W_intra, gate_w, Wint_t);
    convw_k<0><<<dim3(4608), b256, 0, stream>>>(Wz, cw16, 256*KC);
    convw_k<0><<<dim3(4608), b256, 0, stream>>>(Wr, cw16 + 256L*KC, 256*KC);
    convw_k<0><<<dim3(4608), b256, 0, stream>>>(Wh, cw16 + 512L*KC, 256*KC);
    convw_k<1><<<dim3(4608), b256, 0, stream>>>(ro_w1, cw16 + 768L*KC, 256*KC);  // halves swapped: expects (v,h)

    // initial bf16 prep of h (from backbone) + h half of inpad
    prep_h_k<<<dim3(36,4,3), b256, 0, stream>>>(h, hcp16, hp16);
    padtr_k<<<dim3(36,4,3), b256, 0, stream>>>(h, inpad, 256);

    for (int it = 0; it < 3; ++it) {
        // ---- attention phase ----
        mgemm_k<64><<<dim3(54,4,2), b256, 0, stream>>>(hp16, Wint_t, t16,
            6912, 256,256,256, 65536L, 1769472L, 2, 256);
        fattn_k<<<dim3(24,1,9), dim3(384), 0, stream>>>(t16, ti16, hp16, hcp16, Mb9);
        gatemm_k<<<dim3(2,36,3), b256, 0, stream>>>(gatew16, Mb9, gate_b, inpad);
        // ---- conv phase ----
        cgemm2_k<<<dim3(54,4,2), b256, 0, stream>>>(inpad, cw16, cpart, 512);
        credzr_k<<<dim3(36,4,3), b256, 0, stream>>>(cpart, bz, br, h, zg, inpad);
        cgemm2_k<<<dim3(54,2,2), b256, 0, stream>>>(inpad, cw16 + 512L*KC, cpart, 256);
        credht_k<<<dim3(36,4,3), b256, 0, stream>>>(cpart, bh, zg, h, hcp16, hp16, inpad);
    }

    // ---- readout: h already in inpad[256:512) from last credht; add v at [0:256) ----
    padtr_k<<<dim3(36,4,3), b256, 0, stream>>>(v, inpad, 0);
    cgemm2_k<<<dim3(54,2,2), b256, 0, stream>>>(inpad, cw16 + 768L*KC, cpart, 256);
    credro_k<<<dim3(6912), b256, 0, stream>>>(cpart, ro_b1, zg);
    maskpart_k<<<dim3(27,8), b256, 0, stream>>>(zg, ro_w2, maskp);
    maskred_k<<<dim3(27), b256, 0, stream>>>(maskp, ro_b2, out);
}